// Round 3
// baseline (624.890 us; speedup 1.0000x reference)
//
#include <hip/hip_runtime.h>
#include <stdint.h>

typedef unsigned short u16;
typedef unsigned int u32;

#define T_TOK 8192      // B*S tokens
#define DIMSZ 1024
#define HIDSZ 1024
#define NE 8
#define NSLOT (T_TOK * 2)

typedef __attribute__((ext_vector_type(8))) __bf16 bf16x8;
typedef __attribute__((ext_vector_type(4))) float f32x4;

// async global -> LDS, 16B per lane; LDS dest is wave-uniform base + lane*16
#define GLDS(g, l)                                                   \
  __builtin_amdgcn_global_load_lds(                                  \
      (const __attribute__((address_space(1))) void*)(g),            \
      (__attribute__((address_space(3))) void*)(l), 16, 0, 0)

__device__ __forceinline__ u16 f2bf(float f) {
  u32 u = __builtin_bit_cast(u32, f);
  u += 0x7FFFu + ((u >> 16) & 1u);   // RNE
  return (u16)(u >> 16);
}
__device__ __forceinline__ float bflo(u32 v) { return __builtin_bit_cast(float, v << 16); }
__device__ __forceinline__ float bfhi(u32 v) { return __builtin_bit_cast(float, v & 0xffff0000u); }
__device__ __forceinline__ u32 pack2(float a, float b) {
  return (u32)f2bf(a) | ((u32)f2bf(b) << 16);
}
__device__ __forceinline__ float silu_f(float v) { return v / (1.f + expf(-v)); }

// ---------------- fp32 -> bf16 weight conversion (3 tensors per launch) ------
__global__ __launch_bounds__(256) void convert3_kernel(
    const float* __restrict__ s0, const float* __restrict__ s1,
    const float* __restrict__ s2, u16* __restrict__ d0, u16* __restrict__ d1,
    u16* __restrict__ d2, int n4) {
  const float* s = (blockIdx.y == 0) ? s0 : (blockIdx.y == 1) ? s1 : s2;
  u16* d = (blockIdx.y == 0) ? d0 : (blockIdx.y == 1) ? d1 : d2;
  int stride = gridDim.x * 256;
  for (int i = blockIdx.x * 256 + threadIdx.x; i < n4; i += stride) {
    float4 v = ((const float4*)s)[i];
    uint2 p;
    p.x = pack2(v.x, v.y);
    p.y = pack2(v.z, v.w);
    ((uint2*)d)[i] = p;
  }
}

// ---------------- router: fp32 scores, top-2; emits bf16(x); NO atomics ------
__global__ __launch_bounds__(256) void router_kernel(
    const float* __restrict__ x, const float* __restrict__ gw,
    const float* __restrict__ bias, int* __restrict__ sel,
    float* __restrict__ selscore, u16* __restrict__ xb) {
  int t = blockIdx.x * 4 + (threadIdx.x >> 6);
  int lane = threadIdx.x & 63;
  float a[NE];
#pragma unroll
  for (int e = 0; e < NE; e++) a[e] = 0.f;
#pragma unroll
  for (int j = 0; j < 4; j++) {
    int c = j * 256 + lane * 4;
    float4 xv = *(const float4*)&x[(size_t)t * DIMSZ + c];
    uint2 p;
    p.x = pack2(xv.x, xv.y);
    p.y = pack2(xv.z, xv.w);
    *(uint2*)&xb[(size_t)t * DIMSZ + c] = p;
#pragma unroll
    for (int e = 0; e < NE; e++) {
      float4 gv = *(const float4*)&gw[e * DIMSZ + c];
      a[e] = fmaf(xv.x, gv.x, fmaf(xv.y, gv.y, fmaf(xv.z, gv.z, fmaf(xv.w, gv.w, a[e]))));
    }
  }
#pragma unroll
  for (int off = 1; off < 64; off <<= 1)
#pragma unroll
    for (int e = 0; e < NE; e++) a[e] += __shfl_xor(a[e], off);
  if (lane == 0) {
    float s[NE], b[NE];
#pragma unroll
    for (int e = 0; e < NE; e++) {
      s[e] = 1.f / (1.f + expf(-a[e]));
      b[e] = s[e] + bias[e];
    }
    int e1 = 0; float v1 = b[0];
#pragma unroll
    for (int e = 1; e < NE; e++) if (b[e] > v1) { v1 = b[e]; e1 = e; }
    int e2 = -1; float v2 = -1e30f;
#pragma unroll
    for (int e = 0; e < NE; e++) if (e != e1 && b[e] > v2) { v2 = b[e]; e2 = e; }
    sel[t * 2] = e1; sel[t * 2 + 1] = e2;
    selscore[t * 2] = s[e1];       // ROUTE_SCALE == 1
    selscore[t * 2 + 1] = s[e2];
  }
}

// ---------------- rank: single block, atomic-free dispatch permutation -------
__global__ __launch_bounds__(1024) void rank_kernel(
    const int* __restrict__ sel, const float* __restrict__ selscore,
    int* __restrict__ slot2pos, float* __restrict__ slot_score,
    int* __restrict__ counts, int* __restrict__ offsets) {
  __shared__ int hist[NE * 1024];
  __shared__ int tot[NE];
  __shared__ int offs[NE];
  int tid = threadIdx.x;
  int sl[16];
  int h[NE];
#pragma unroll
  for (int e = 0; e < NE; e++) h[e] = 0;
#pragma unroll
  for (int j = 0; j < 4; j++) {
    int4 v = ((const int4*)sel)[tid * 4 + j];
    sl[j * 4 + 0] = v.x; sl[j * 4 + 1] = v.y;
    sl[j * 4 + 2] = v.z; sl[j * 4 + 3] = v.w;
  }
#pragma unroll
  for (int i = 0; i < 16; i++)
#pragma unroll
    for (int e = 0; e < NE; e++) h[e] += (sl[i] == e) ? 1 : 0;
#pragma unroll
  for (int e = 0; e < NE; e++) hist[e * 1024 + tid] = h[e];
  __syncthreads();
  int wid = tid >> 6, lane = tid & 63;
  if (wid < NE) {
    int e = wid;
    int vals[16];
    int lsum = 0;
#pragma unroll
    for (int i = 0; i < 16; i++) {
      int v = hist[e * 1024 + lane * 16 + i];
      vals[i] = lsum;
      lsum += v;
    }
    int incl = lsum;
#pragma unroll
    for (int off = 1; off < 64; off <<= 1) {
      int v = __shfl_up(incl, off);
      if (lane >= off) incl += v;
    }
    int excl = incl - lsum;
#pragma unroll
    for (int i = 0; i < 16; i++) hist[e * 1024 + lane * 16 + i] = vals[i] + excl;
    if (lane == 63) tot[e] = incl;
  }
  __syncthreads();
  if (tid == 0) {
    int acc = 0;
    for (int e = 0; e < NE; e++) {
      offs[e] = acc;
      offsets[e] = acc;
      counts[e] = tot[e];
      acc += tot[e];
    }
  }
  __syncthreads();
  int base[NE];
#pragma unroll
  for (int e = 0; e < NE; e++) base[e] = offs[e] + hist[e * 1024 + tid];
#pragma unroll
  for (int i = 0; i < 16; i++) {
    int slot = tid * 16 + i;
    int e = sl[i];
    int pos = 0;
#pragma unroll
    for (int k = 0; k < NE; k++) pos += (e == k) ? base[k] : 0;
#pragma unroll
    for (int k = 0; k < NE; k++) base[k] += (e == k) ? 1 : 0;
    slot2pos[slot] = pos;
    slot_score[pos] = selscore[slot];
  }
}

// ---------------- gather: pure copy, slot -> row pos of bf16(s*x) ------------
__global__ __launch_bounds__(256) void gather_kernel(
    const float* __restrict__ x, const float* __restrict__ selscore,
    const int* __restrict__ slot2pos, u16* __restrict__ routed) {
  int s = blockIdx.x * 4 + (threadIdx.x >> 6);
  int lane = threadIdx.x & 63;
  int pos = slot2pos[s];
  float sc = selscore[s];
  int t = s >> 1;
#pragma unroll
  for (int j = 0; j < 4; j++) {
    int c = j * 256 + lane * 4;
    float4 v = *(const float4*)&x[(size_t)t * DIMSZ + c];
    uint2 p;
    p.x = pack2(v.x * sc, v.y * sc);
    p.y = pack2(v.z * sc, v.w * sc);
    *(uint2*)&routed[(size_t)pos * DIMSZ + c] = p;
  }
}

// ---------------- dual GEMM (G1,G3 share A-tile) + silu*mul -> H bf16 --------
// BM=128 BN=64 BK=32, 256 thr = 4 waves, mfma_f32_16x16x32_bf16.
// Staging via global_load_lds width=16: wave w stages k-chunk w.
__global__ __launch_bounds__(256) void dual_glu_gemm(
    const u16* __restrict__ A, const u16* __restrict__ W1,
    const u16* __restrict__ W3, u16* __restrict__ Hout,
    const int* __restrict__ seg_off, const int* __restrict__ seg_cnt, int fullM) {
  int z = blockIdx.z;
  int soff = 0, scnt = fullM;
  if (seg_off) { soff = seg_off[z]; scnt = seg_cnt[z]; }
  int mbase = blockIdx.y * 128;
  if (mbase >= scnt) return;
  int nbase = blockIdx.x * 64;
  const u16* w1p = W1 + (size_t)z * HIDSZ * DIMSZ;
  const u16* w3p = W3 + (size_t)z * HIDSZ * DIMSZ;

  __shared__ u16 lA[4 * 128 * 8];
  __shared__ u16 lB1[4 * 64 * 8];
  __shared__ u16 lB3[4 * 64 * 8];

  int tid = threadIdx.x;
  int lane = tid & 63;
  int wid = tid >> 6;
  int wy = wid >> 1, wx = wid & 1;
  int q = lane >> 4, lm = lane & 15;

  f32x4 acc1[4][2], acc3[4][2];
#pragma unroll
  for (int i = 0; i < 4; i++)
#pragma unroll
    for (int j = 0; j < 2; j++) { acc1[i][j] = (f32x4)0.f; acc3[i][j] = (f32x4)0.f; }

  // staging addresses: wave wid stages k-chunk wid (rows clamped; garbage rows
  // are masked at the epilogue)
  int r0 = min(mbase + lane, scnt - 1);
  int r1 = min(mbase + 64 + lane, scnt - 1);
  const u16* gA0 = A + (size_t)(soff + r0) * DIMSZ + wid * 8;
  const u16* gA1 = A + (size_t)(soff + r1) * DIMSZ + wid * 8;
  const u16* gB1 = w1p + (size_t)(nbase + lane) * DIMSZ + wid * 8;
  const u16* gB3 = w3p + (size_t)(nbase + lane) * DIMSZ + wid * 8;
  u16* dA0 = &lA[(wid * 128 + 0) * 8];
  u16* dA1 = &lA[(wid * 128 + 64) * 8];
  u16* dB1 = &lB1[(wid * 64) * 8];
  u16* dB3 = &lB3[(wid * 64) * 8];

  for (int kt = 0; kt < DIMSZ / 32; kt++) {
    GLDS(gA0, dA0);
    GLDS(gA1, dA1);
    GLDS(gB1, dB1);
    GLDS(gB3, dB3);
    gA0 += 32; gA1 += 32; gB1 += 32; gB3 += 32;
    __syncthreads();
    bf16x8 af[4];
#pragma unroll
    for (int i = 0; i < 4; i++)
      af[i] = *(const bf16x8*)&lA[(q * 128 + wy * 64 + i * 16 + lm) * 8];
    bf16x8 b1f[2], b3f[2];
#pragma unroll
    for (int j = 0; j < 2; j++) {
      b1f[j] = *(const bf16x8*)&lB1[(q * 64 + wx * 32 + j * 16 + lm) * 8];
      b3f[j] = *(const bf16x8*)&lB3[(q * 64 + wx * 32 + j * 16 + lm) * 8];
    }
#pragma unroll
    for (int i = 0; i < 4; i++)
#pragma unroll
      for (int j = 0; j < 2; j++) {
        acc1[i][j] = __builtin_amdgcn_mfma_f32_16x16x32_bf16(af[i], b1f[j], acc1[i][j], 0, 0, 0);
        acc3[i][j] = __builtin_amdgcn_mfma_f32_16x16x32_bf16(af[i], b3f[j], acc3[i][j], 0, 0, 0);
      }
    __syncthreads();
  }
#pragma unroll
  for (int i = 0; i < 4; i++) {
    int rowb = mbase + wy * 64 + i * 16 + q * 4;
#pragma unroll
    for (int j = 0; j < 2; j++) {
      int col = nbase + wx * 32 + j * 16 + lm;
      f32x4 g1 = acc1[i][j], g3 = acc3[i][j];
#pragma unroll
      for (int r = 0; r < 4; r++) {
        int grow = rowb + r;
        if (grow < scnt)
          Hout[(size_t)(soff + grow) * HIDSZ + col] = f2bf(silu_f(g1[r]) * g3[r]);
      }
    }
  }
}

// ---------------- GEMM2: Out = (A @ W^T) * scale, BM=128 BN=128 BK=32 --------
template <bool OUT_BF16>
__global__ __launch_bounds__(256) void gemm2_kernel(
    const u16* __restrict__ A, const u16* __restrict__ W, void* __restrict__ Out,
    const float* __restrict__ scale, const int* __restrict__ seg_off,
    const int* __restrict__ seg_cnt, int fullM) {
  int z = blockIdx.z;
  int soff = 0, scnt = fullM;
  if (seg_off) { soff = seg_off[z]; scnt = seg_cnt[z]; }
  int mbase = blockIdx.y * 128;
  if (mbase >= scnt) return;
  int nbase = blockIdx.x * 128;
  const u16* wp = W + (size_t)z * DIMSZ * HIDSZ;

  __shared__ u16 lA[4 * 128 * 8];
  __shared__ u16 lB[4 * 128 * 8];

  int tid = threadIdx.x;
  int lane = tid & 63;
  int wid = tid >> 6;
  int wy = wid >> 1, wx = wid & 1;
  int q = lane >> 4, lm = lane & 15;

  f32x4 acc[4][4];
#pragma unroll
  for (int i = 0; i < 4; i++)
#pragma unroll
    for (int j = 0; j < 4; j++) acc[i][j] = (f32x4)0.f;

  int r0 = min(mbase + lane, scnt - 1);
  int r1 = min(mbase + 64 + lane, scnt - 1);
  const u16* gA0 = A + (size_t)(soff + r0) * HIDSZ + wid * 8;
  const u16* gA1 = A + (size_t)(soff + r1) * HIDSZ + wid * 8;
  const u16* gB0 = wp + (size_t)(nbase + lane) * HIDSZ + wid * 8;
  const u16* gB1 = wp + (size_t)(nbase + 64 + lane) * HIDSZ + wid * 8;
  u16* dA0 = &lA[(wid * 128 + 0) * 8];
  u16* dA1 = &lA[(wid * 128 + 64) * 8];
  u16* dB0 = &lB[(wid * 128 + 0) * 8];
  u16* dB1 = &lB[(wid * 128 + 64) * 8];

  for (int kt = 0; kt < HIDSZ / 32; kt++) {
    GLDS(gA0, dA0);
    GLDS(gA1, dA1);
    GLDS(gB0, dB0);
    GLDS(gB1, dB1);
    gA0 += 32; gA1 += 32; gB0 += 32; gB1 += 32;
    __syncthreads();
    bf16x8 af[4], bf[4];
#pragma unroll
    for (int i = 0; i < 4; i++) {
      af[i] = *(const bf16x8*)&lA[(q * 128 + wy * 64 + i * 16 + lm) * 8];
      bf[i] = *(const bf16x8*)&lB[(q * 128 + wx * 64 + i * 16 + lm) * 8];
    }
#pragma unroll
    for (int i = 0; i < 4; i++)
#pragma unroll
      for (int j = 0; j < 4; j++)
        acc[i][j] = __builtin_amdgcn_mfma_f32_16x16x32_bf16(af[i], bf[j], acc[i][j], 0, 0, 0);
    __syncthreads();
  }
#pragma unroll
  for (int i = 0; i < 4; i++) {
    int rowb = mbase + wy * 64 + i * 16 + q * 4;
#pragma unroll
    for (int j = 0; j < 4; j++) {
      int col = nbase + wx * 64 + j * 16 + lm;
      f32x4 a = acc[i][j];
#pragma unroll
      for (int r = 0; r < 4; r++) {
        int grow = rowb + r;
        if (grow < scnt) {
          float s = scale ? scale[soff + grow] : 1.f;
          float v = a[r] * s;
          size_t idx = (size_t)(soff + grow) * DIMSZ + col;
          if (OUT_BF16) ((u16*)Out)[idx] = f2bf(v);
          else ((float*)Out)[idx] = v;
        }
      }
    }
  }
}

// ---------------- combine: out[t] += Or[pos(t,0)] + Or[pos(t,1)] -------------
__global__ __launch_bounds__(256) void combine_kernel(
    float* __restrict__ out, const u16* __restrict__ Orb,
    const int* __restrict__ slot2pos) {
  int t = blockIdx.x;
  int d = threadIdx.x * 4;
  int p0 = slot2pos[t * 2];
  int p1 = slot2pos[t * 2 + 1];
  float4 o = *(float4*)&out[(size_t)t * DIMSZ + d];
  uint2 a = *(const uint2*)&Orb[(size_t)p0 * DIMSZ + d];
  uint2 b = *(const uint2*)&Orb[(size_t)p1 * DIMSZ + d];
  o.x += bflo(a.x) + bflo(b.x);
  o.y += bfhi(a.x) + bfhi(b.x);
  o.z += bflo(a.y) + bflo(b.y);
  o.w += bfhi(a.y) + bfhi(b.y);
  *(float4*)&out[(size_t)t * DIMSZ + d] = o;
}

extern "C" void kernel_launch(void* const* d_in, const int* in_sizes, int n_in,
                              void* d_out, int out_size, void* d_ws, size_t ws_size,
                              hipStream_t stream) {
  const float* x = (const float*)d_in[0];
  const float* gw = (const float*)d_in[1];
  const float* w1 = (const float*)d_in[2];
  const float* w2 = (const float*)d_in[3];
  const float* w3 = (const float*)d_in[4];
  const float* sw1 = (const float*)d_in[5];
  const float* sw2 = (const float*)d_in[6];
  const float* sw3 = (const float*)d_in[7];
  const float* bias = (const float*)d_in[8];
  float* out = (float*)d_out;

  uint8_t* ws = (uint8_t*)d_ws;
  size_t off = 0;
  auto alloc = [&](size_t b) { size_t o = off; off += (b + 255) & ~(size_t)255; return o; };

  size_t ctrl = alloc(256);
  int* counts = (int*)(ws + ctrl);
  int* offsets = counts + 16;
  int* sel = (int*)(ws + alloc((size_t)NSLOT * 4));
  float* selscore = (float*)(ws + alloc((size_t)NSLOT * 4));
  float* slot_score = (float*)(ws + alloc((size_t)NSLOT * 4));
  int* slot2pos = (int*)(ws + alloc((size_t)NSLOT * 4));
  u16* xb = (u16*)(ws + alloc((size_t)T_TOK * DIMSZ * 2));
  u16* routed = (u16*)(ws + alloc((size_t)NSLOT * DIMSZ * 2));
  u16* Hbuf = (u16*)(ws + alloc((size_t)NSLOT * HIDSZ * 2));
  u16* Orb = (u16*)(ws + alloc((size_t)NSLOT * DIMSZ * 2));
  u16* Hs = (u16*)(ws + alloc((size_t)T_TOK * HIDSZ * 2));
  u16* w1b = (u16*)(ws + alloc((size_t)NE * HIDSZ * DIMSZ * 2));
  u16* w2b = (u16*)(ws + alloc((size_t)NE * DIMSZ * HIDSZ * 2));
  u16* w3b = (u16*)(ws + alloc((size_t)NE * HIDSZ * DIMSZ * 2));
  u16* sw1b = (u16*)(ws + alloc((size_t)HIDSZ * DIMSZ * 2));
  u16* sw2b = (u16*)(ws + alloc((size_t)DIMSZ * HIDSZ * 2));
  u16* sw3b = (u16*)(ws + alloc((size_t)HIDSZ * DIMSZ * 2));

  // weight conversion (fp32 -> bf16)
  convert3_kernel<<<dim3(2048, 3), 256, 0, stream>>>(
      w1, w2, w3, w1b, w2b, w3b, NE * HIDSZ * DIMSZ / 4);
  convert3_kernel<<<dim3(512, 3), 256, 0, stream>>>(
      sw1, sw2, sw3, sw1b, sw2b, sw3b, HIDSZ * DIMSZ / 4);

  router_kernel<<<T_TOK / 4, 256, 0, stream>>>(x, gw, bias, sel, selscore, xb);
  rank_kernel<<<1, 1024, 0, stream>>>(sel, selscore, slot2pos, slot_score,
                                      counts, offsets);
  gather_kernel<<<NSLOT / 4, 256, 0, stream>>>(x, selscore, slot2pos, routed);

  // routed experts
  dual_glu_gemm<<<dim3(16, 64, 8), 256, 0, stream>>>(routed, w1b, w3b, Hbuf,
                                                     offsets, counts, 0);
  gemm2_kernel<true><<<dim3(8, 64, 8), 256, 0, stream>>>(Hbuf, w2b, (void*)Orb,
                                                         slot_score, offsets, counts, 0);
  // shared expert (writes d_out directly)
  dual_glu_gemm<<<dim3(16, 64, 1), 256, 0, stream>>>(xb, sw1b, sw3b, Hs,
                                                     nullptr, nullptr, T_TOK);
  gemm2_kernel<false><<<dim3(8, 64, 1), 256, 0, stream>>>(Hs, sw2b, (void*)d_out,
                                                          nullptr, nullptr, nullptr, T_TOK);
  // combine routed contributions into shared output
  combine_kernel<<<T_TOK, 256, 0, stream>>>(out, Orb, slot2pos);
}

// Round 4
// 523.355 us; speedup vs baseline: 1.1940x; 1.1940x over previous
//
#include <hip/hip_runtime.h>
#include <stdint.h>

typedef unsigned short u16;
typedef unsigned int u32;

#define T_TOK 8192      // B*S tokens
#define DIMSZ 1024
#define HIDSZ 1024
#define NE 8
#define NSLOT (T_TOK * 2)

typedef __attribute__((ext_vector_type(8))) __bf16 bf16x8;
typedef __attribute__((ext_vector_type(4))) float f32x4;

// swizzled LDS index (in u16 units) for tile element (row, kchunk):
// row*64B + ((kc ^ (row&3)) * 16B). Writes: 4-lane clusters hit 4 distinct
// bank groups; reads: min-aliasing only (measured-0-conflict class).
__device__ __forceinline__ int sw_idx(int row, int kc) {
  return row * 32 + ((kc ^ (row & 3)) * 8);
}

__device__ __forceinline__ u16 f2bf(float f) {
  u32 u = __builtin_bit_cast(u32, f);
  u += 0x7FFFu + ((u >> 16) & 1u);   // RNE
  return (u16)(u >> 16);
}
__device__ __forceinline__ float bflo(u32 v) { return __builtin_bit_cast(float, v << 16); }
__device__ __forceinline__ float bfhi(u32 v) { return __builtin_bit_cast(float, v & 0xffff0000u); }
__device__ __forceinline__ u32 pack2(float a, float b) {
  return (u32)f2bf(a) | ((u32)f2bf(b) << 16);
}
__device__ __forceinline__ float silu_f(float v) { return v / (1.f + expf(-v)); }

// ---------------- fp32 -> bf16 weight conversion (3 tensors per launch) ------
__global__ __launch_bounds__(256) void convert3_kernel(
    const float* __restrict__ s0, const float* __restrict__ s1,
    const float* __restrict__ s2, u16* __restrict__ d0, u16* __restrict__ d1,
    u16* __restrict__ d2, int n4) {
  const float* s = (blockIdx.y == 0) ? s0 : (blockIdx.y == 1) ? s1 : s2;
  u16* d = (blockIdx.y == 0) ? d0 : (blockIdx.y == 1) ? d1 : d2;
  int stride = gridDim.x * 256;
  for (int i = blockIdx.x * 256 + threadIdx.x; i < n4; i += stride) {
    float4 v = ((const float4*)s)[i];
    uint2 p;
    p.x = pack2(v.x, v.y);
    p.y = pack2(v.z, v.w);
    ((uint2*)d)[i] = p;
  }
}

// ---------------- router: fp32 scores, top-2; emits bf16(x); NO atomics ------
__global__ __launch_bounds__(256) void router_kernel(
    const float* __restrict__ x, const float* __restrict__ gw,
    const float* __restrict__ bias, int* __restrict__ sel,
    float* __restrict__ selscore, u16* __restrict__ xb) {
  int t = blockIdx.x * 4 + (threadIdx.x >> 6);
  int lane = threadIdx.x & 63;
  float a[NE];
#pragma unroll
  for (int e = 0; e < NE; e++) a[e] = 0.f;
#pragma unroll
  for (int j = 0; j < 4; j++) {
    int c = j * 256 + lane * 4;
    float4 xv = *(const float4*)&x[(size_t)t * DIMSZ + c];
    uint2 p;
    p.x = pack2(xv.x, xv.y);
    p.y = pack2(xv.z, xv.w);
    *(uint2*)&xb[(size_t)t * DIMSZ + c] = p;
#pragma unroll
    for (int e = 0; e < NE; e++) {
      float4 gv = *(const float4*)&gw[e * DIMSZ + c];
      a[e] = fmaf(xv.x, gv.x, fmaf(xv.y, gv.y, fmaf(xv.z, gv.z, fmaf(xv.w, gv.w, a[e]))));
    }
  }
#pragma unroll
  for (int off = 1; off < 64; off <<= 1)
#pragma unroll
    for (int e = 0; e < NE; e++) a[e] += __shfl_xor(a[e], off);
  if (lane == 0) {
    float s[NE], b[NE];
#pragma unroll
    for (int e = 0; e < NE; e++) {
      s[e] = 1.f / (1.f + expf(-a[e]));
      b[e] = s[e] + bias[e];
    }
    int e1 = 0; float v1 = b[0];
#pragma unroll
    for (int e = 1; e < NE; e++) if (b[e] > v1) { v1 = b[e]; e1 = e; }
    int e2 = -1; float v2 = -1e30f;
#pragma unroll
    for (int e = 0; e < NE; e++) if (e != e1 && b[e] > v2) { v2 = b[e]; e2 = e; }
    sel[t * 2] = e1; sel[t * 2 + 1] = e2;
    selscore[t * 2] = s[e1];       // ROUTE_SCALE == 1
    selscore[t * 2 + 1] = s[e2];
  }
}

// ---------------- rank: single block, atomic-free dispatch permutation -------
__global__ __launch_bounds__(1024) void rank_kernel(
    const int* __restrict__ sel, const float* __restrict__ selscore,
    int* __restrict__ slot2pos, float* __restrict__ slot_score,
    int* __restrict__ counts, int* __restrict__ offsets) {
  __shared__ int hist[NE * 1024];
  __shared__ int tot[NE];
  __shared__ int offs[NE];
  int tid = threadIdx.x;
  int sl[16];
  int h[NE];
#pragma unroll
  for (int e = 0; e < NE; e++) h[e] = 0;
#pragma unroll
  for (int j = 0; j < 4; j++) {
    int4 v = ((const int4*)sel)[tid * 4 + j];
    sl[j * 4 + 0] = v.x; sl[j * 4 + 1] = v.y;
    sl[j * 4 + 2] = v.z; sl[j * 4 + 3] = v.w;
  }
#pragma unroll
  for (int i = 0; i < 16; i++)
#pragma unroll
    for (int e = 0; e < NE; e++) h[e] += (sl[i] == e) ? 1 : 0;
#pragma unroll
  for (int e = 0; e < NE; e++) hist[e * 1024 + tid] = h[e];
  __syncthreads();
  int wid = tid >> 6, lane = tid & 63;
  if (wid < NE) {
    int e = wid;
    int vals[16];
    int lsum = 0;
#pragma unroll
    for (int i = 0; i < 16; i++) {
      int v = hist[e * 1024 + lane * 16 + i];
      vals[i] = lsum;
      lsum += v;
    }
    int incl = lsum;
#pragma unroll
    for (int off = 1; off < 64; off <<= 1) {
      int v = __shfl_up(incl, off);
      if (lane >= off) incl += v;
    }
    int excl = incl - lsum;
#pragma unroll
    for (int i = 0; i < 16; i++) hist[e * 1024 + lane * 16 + i] = vals[i] + excl;
    if (lane == 63) tot[e] = incl;
  }
  __syncthreads();
  if (tid == 0) {
    int acc = 0;
    for (int e = 0; e < NE; e++) {
      offs[e] = acc;
      offsets[e] = acc;
      counts[e] = tot[e];
      acc += tot[e];
    }
  }
  __syncthreads();
  int base[NE];
#pragma unroll
  for (int e = 0; e < NE; e++) base[e] = offs[e] + hist[e * 1024 + tid];
#pragma unroll
  for (int i = 0; i < 16; i++) {
    int slot = tid * 16 + i;
    int e = sl[i];
    int pos = 0;
#pragma unroll
    for (int k = 0; k < NE; k++) pos += (e == k) ? base[k] : 0;
#pragma unroll
    for (int k = 0; k < NE; k++) base[k] += (e == k) ? 1 : 0;
    slot2pos[slot] = pos;
    slot_score[pos] = selscore[slot];
  }
}

// ---------------- gather: pure copy, slot -> row pos of bf16(s*x) ------------
__global__ __launch_bounds__(256) void gather_kernel(
    const float* __restrict__ x, const float* __restrict__ selscore,
    const int* __restrict__ slot2pos, u16* __restrict__ routed) {
  int s = blockIdx.x * 4 + (threadIdx.x >> 6);
  int lane = threadIdx.x & 63;
  int pos = slot2pos[s];
  float sc = selscore[s];
  int t = s >> 1;
#pragma unroll
  for (int j = 0; j < 4; j++) {
    int c = j * 256 + lane * 4;
    float4 v = *(const float4*)&x[(size_t)t * DIMSZ + c];
    uint2 p;
    p.x = pack2(v.x * sc, v.y * sc);
    p.y = pack2(v.z * sc, v.w * sc);
    *(uint2*)&routed[(size_t)pos * DIMSZ + c] = p;
  }
}

// ---------------- dual GEMM (G1,G3 share A-tile) + silu*mul -> H bf16 --------
// BM=128 BN=64 BK=32, 256 thr = 4 waves, mfma_f32_16x16x32_bf16.
// Plain uint4 staging (compiler pipelines loads) + XOR-swizzled LDS layout.
__global__ __launch_bounds__(256) void dual_glu_gemm(
    const u16* __restrict__ A, const u16* __restrict__ W1,
    const u16* __restrict__ W3, u16* __restrict__ Hout,
    const int* __restrict__ seg_off, const int* __restrict__ seg_cnt, int fullM) {
  int z = blockIdx.z;
  int soff = 0, scnt = fullM;
  if (seg_off) { soff = seg_off[z]; scnt = seg_cnt[z]; }
  int mbase = blockIdx.y * 128;
  if (mbase >= scnt) return;
  int nbase = blockIdx.x * 64;
  const u16* w1p = W1 + (size_t)z * HIDSZ * DIMSZ;
  const u16* w3p = W3 + (size_t)z * HIDSZ * DIMSZ;

  __shared__ u16 lA[128 * 32];
  __shared__ u16 lB1[64 * 32];
  __shared__ u16 lB3[64 * 32];

  int tid = threadIdx.x;
  int lane = tid & 63;
  int wid = tid >> 6;
  int wy = wid >> 1, wx = wid & 1;
  int q = lane >> 4, lm = lane & 15;

  f32x4 acc1[4][2], acc3[4][2];
#pragma unroll
  for (int i = 0; i < 4; i++)
#pragma unroll
    for (int j = 0; j < 2; j++) { acc1[i][j] = (f32x4)0.f; acc3[i][j] = (f32x4)0.f; }

  int arow = tid >> 2, akc = tid & 3;
  // clamped global rows (garbage rows masked at epilogue)
  int rg0 = min(mbase + arow, scnt - 1);
  int rg1 = min(mbase + arow + 64, scnt - 1);
  const u16* gA0 = A + (size_t)(soff + rg0) * DIMSZ + akc * 8;
  const u16* gA1 = A + (size_t)(soff + rg1) * DIMSZ + akc * 8;
  const u16* gB1 = w1p + (size_t)(nbase + arow) * DIMSZ + akc * 8;
  const u16* gB3 = w3p + (size_t)(nbase + arow) * DIMSZ + akc * 8;
  int sA0 = sw_idx(arow, akc), sA1 = sw_idx(arow + 64, akc);
  int sB = sw_idx(arow, akc);

  for (int kt = 0; kt < DIMSZ / 32; kt++) {
    uint4 vA0 = *(const uint4*)gA0;
    uint4 vA1 = *(const uint4*)gA1;
    uint4 vB1 = *(const uint4*)gB1;
    uint4 vB3 = *(const uint4*)gB3;
    gA0 += 32; gA1 += 32; gB1 += 32; gB3 += 32;
    *(uint4*)&lA[sA0] = vA0;
    *(uint4*)&lA[sA1] = vA1;
    *(uint4*)&lB1[sB] = vB1;
    *(uint4*)&lB3[sB] = vB3;
    __syncthreads();
    bf16x8 af[4];
#pragma unroll
    for (int i = 0; i < 4; i++) {
      int row = wy * 64 + i * 16 + lm;
      af[i] = *(const bf16x8*)&lA[sw_idx(row, q)];
    }
    bf16x8 b1f[2], b3f[2];
#pragma unroll
    for (int j = 0; j < 2; j++) {
      int col = wx * 32 + j * 16 + lm;
      b1f[j] = *(const bf16x8*)&lB1[sw_idx(col, q)];
      b3f[j] = *(const bf16x8*)&lB3[sw_idx(col, q)];
    }
#pragma unroll
    for (int i = 0; i < 4; i++)
#pragma unroll
      for (int j = 0; j < 2; j++) {
        acc1[i][j] = __builtin_amdgcn_mfma_f32_16x16x32_bf16(af[i], b1f[j], acc1[i][j], 0, 0, 0);
        acc3[i][j] = __builtin_amdgcn_mfma_f32_16x16x32_bf16(af[i], b3f[j], acc3[i][j], 0, 0, 0);
      }
    __syncthreads();
  }
#pragma unroll
  for (int i = 0; i < 4; i++) {
    int rowb = mbase + wy * 64 + i * 16 + q * 4;
#pragma unroll
    for (int j = 0; j < 2; j++) {
      int col = nbase + wx * 32 + j * 16 + lm;
      f32x4 g1 = acc1[i][j], g3 = acc3[i][j];
#pragma unroll
      for (int r = 0; r < 4; r++) {
        int grow = rowb + r;
        if (grow < scnt)
          Hout[(size_t)(soff + grow) * HIDSZ + col] = f2bf(silu_f(g1[r]) * g3[r]);
      }
    }
  }
}

// ---------------- GEMM2: Out = (A @ W^T) * scale, BM=128 BN=128 BK=32 --------
template <bool OUT_BF16>
__global__ __launch_bounds__(256) void gemm2_kernel(
    const u16* __restrict__ A, const u16* __restrict__ W, void* __restrict__ Out,
    const float* __restrict__ scale, const int* __restrict__ seg_off,
    const int* __restrict__ seg_cnt, int fullM) {
  int z = blockIdx.z;
  int soff = 0, scnt = fullM;
  if (seg_off) { soff = seg_off[z]; scnt = seg_cnt[z]; }
  int mbase = blockIdx.y * 128;
  if (mbase >= scnt) return;
  int nbase = blockIdx.x * 128;
  const u16* wp = W + (size_t)z * DIMSZ * HIDSZ;

  __shared__ u16 lA[128 * 32];
  __shared__ u16 lB[128 * 32];

  int tid = threadIdx.x;
  int lane = tid & 63;
  int wid = tid >> 6;
  int wy = wid >> 1, wx = wid & 1;
  int q = lane >> 4, lm = lane & 15;

  f32x4 acc[4][4];
#pragma unroll
  for (int i = 0; i < 4; i++)
#pragma unroll
    for (int j = 0; j < 4; j++) acc[i][j] = (f32x4)0.f;

  int arow = tid >> 2, akc = tid & 3;
  int rg0 = min(mbase + arow, scnt - 1);
  int rg1 = min(mbase + arow + 64, scnt - 1);
  const u16* gA0 = A + (size_t)(soff + rg0) * HIDSZ + akc * 8;
  const u16* gA1 = A + (size_t)(soff + rg1) * HIDSZ + akc * 8;
  const u16* gB0 = wp + (size_t)(nbase + arow) * HIDSZ + akc * 8;
  const u16* gB1 = wp + (size_t)(nbase + arow + 64) * HIDSZ + akc * 8;
  int s0 = sw_idx(arow, akc), s1 = sw_idx(arow + 64, akc);

  for (int kt = 0; kt < HIDSZ / 32; kt++) {
    uint4 vA0 = *(const uint4*)gA0;
    uint4 vA1 = *(const uint4*)gA1;
    uint4 vB0 = *(const uint4*)gB0;
    uint4 vB1 = *(const uint4*)gB1;
    gA0 += 32; gA1 += 32; gB0 += 32; gB1 += 32;
    *(uint4*)&lA[s0] = vA0;
    *(uint4*)&lA[s1] = vA1;
    *(uint4*)&lB[s0] = vB0;
    *(uint4*)&lB[s1] = vB1;
    __syncthreads();
    bf16x8 af[4], bf[4];
#pragma unroll
    for (int i = 0; i < 4; i++) {
      int row = wy * 64 + i * 16 + lm;
      int col = wx * 64 + i * 16 + lm;
      af[i] = *(const bf16x8*)&lA[sw_idx(row, q)];
      bf[i] = *(const bf16x8*)&lB[sw_idx(col, q)];
    }
#pragma unroll
    for (int i = 0; i < 4; i++)
#pragma unroll
      for (int j = 0; j < 4; j++)
        acc[i][j] = __builtin_amdgcn_mfma_f32_16x16x32_bf16(af[i], bf[j], acc[i][j], 0, 0, 0);
    __syncthreads();
  }
#pragma unroll
  for (int i = 0; i < 4; i++) {
    int rowb = mbase + wy * 64 + i * 16 + q * 4;
#pragma unroll
    for (int j = 0; j < 4; j++) {
      int col = nbase + wx * 64 + j * 16 + lm;
      f32x4 a = acc[i][j];
#pragma unroll
      for (int r = 0; r < 4; r++) {
        int grow = rowb + r;
        if (grow < scnt) {
          float s = scale ? scale[soff + grow] : 1.f;
          float v = a[r] * s;
          size_t idx = (size_t)(soff + grow) * DIMSZ + col;
          if (OUT_BF16) ((u16*)Out)[idx] = f2bf(v);
          else ((float*)Out)[idx] = v;
        }
      }
    }
  }
}

// ---------------- combine: out[t] += Or[pos(t,0)] + Or[pos(t,1)] -------------
__global__ __launch_bounds__(256) void combine_kernel(
    float* __restrict__ out, const u16* __restrict__ Orb,
    const int* __restrict__ slot2pos) {
  int t = blockIdx.x;
  int d = threadIdx.x * 4;
  int p0 = slot2pos[t * 2];
  int p1 = slot2pos[t * 2 + 1];
  float4 o = *(float4*)&out[(size_t)t * DIMSZ + d];
  uint2 a = *(const uint2*)&Orb[(size_t)p0 * DIMSZ + d];
  uint2 b = *(const uint2*)&Orb[(size_t)p1 * DIMSZ + d];
  o.x += bflo(a.x) + bflo(b.x);
  o.y += bfhi(a.x) + bfhi(b.x);
  o.z += bflo(a.y) + bflo(b.y);
  o.w += bfhi(a.y) + bfhi(b.y);
  *(float4*)&out[(size_t)t * DIMSZ + d] = o;
}

extern "C" void kernel_launch(void* const* d_in, const int* in_sizes, int n_in,
                              void* d_out, int out_size, void* d_ws, size_t ws_size,
                              hipStream_t stream) {
  const float* x = (const float*)d_in[0];
  const float* gw = (const float*)d_in[1];
  const float* w1 = (const float*)d_in[2];
  const float* w2 = (const float*)d_in[3];
  const float* w3 = (const float*)d_in[4];
  const float* sw1 = (const float*)d_in[5];
  const float* sw2 = (const float*)d_in[6];
  const float* sw3 = (const float*)d_in[7];
  const float* bias = (const float*)d_in[8];
  float* out = (float*)d_out;

  uint8_t* ws = (uint8_t*)d_ws;
  size_t off = 0;
  auto alloc = [&](size_t b) { size_t o = off; off += (b + 255) & ~(size_t)255; return o; };

  size_t ctrl = alloc(256);
  int* counts = (int*)(ws + ctrl);
  int* offsets = counts + 16;
  int* sel = (int*)(ws + alloc((size_t)NSLOT * 4));
  float* selscore = (float*)(ws + alloc((size_t)NSLOT * 4));
  float* slot_score = (float*)(ws + alloc((size_t)NSLOT * 4));
  int* slot2pos = (int*)(ws + alloc((size_t)NSLOT * 4));
  u16* xb = (u16*)(ws + alloc((size_t)T_TOK * DIMSZ * 2));
  u16* routed = (u16*)(ws + alloc((size_t)NSLOT * DIMSZ * 2));
  u16* Hbuf = (u16*)(ws + alloc((size_t)NSLOT * HIDSZ * 2));
  u16* Orb = (u16*)(ws + alloc((size_t)NSLOT * DIMSZ * 2));
  u16* Hs = (u16*)(ws + alloc((size_t)T_TOK * HIDSZ * 2));
  u16* w1b = (u16*)(ws + alloc((size_t)NE * HIDSZ * DIMSZ * 2));
  u16* w2b = (u16*)(ws + alloc((size_t)NE * DIMSZ * HIDSZ * 2));
  u16* w3b = (u16*)(ws + alloc((size_t)NE * HIDSZ * DIMSZ * 2));
  u16* sw1b = (u16*)(ws + alloc((size_t)HIDSZ * DIMSZ * 2));
  u16* sw2b = (u16*)(ws + alloc((size_t)DIMSZ * HIDSZ * 2));
  u16* sw3b = (u16*)(ws + alloc((size_t)HIDSZ * DIMSZ * 2));

  // weight conversion (fp32 -> bf16)
  convert3_kernel<<<dim3(2048, 3), 256, 0, stream>>>(
      w1, w2, w3, w1b, w2b, w3b, NE * HIDSZ * DIMSZ / 4);
  convert3_kernel<<<dim3(512, 3), 256, 0, stream>>>(
      sw1, sw2, sw3, sw1b, sw2b, sw3b, HIDSZ * DIMSZ / 4);

  router_kernel<<<T_TOK / 4, 256, 0, stream>>>(x, gw, bias, sel, selscore, xb);
  rank_kernel<<<1, 1024, 0, stream>>>(sel, selscore, slot2pos, slot_score,
                                      counts, offsets);
  gather_kernel<<<NSLOT / 4, 256, 0, stream>>>(x, selscore, slot2pos, routed);

  // routed experts
  dual_glu_gemm<<<dim3(16, 64, 8), 256, 0, stream>>>(routed, w1b, w3b, Hbuf,
                                                     offsets, counts, 0);
  gemm2_kernel<true><<<dim3(8, 64, 8), 256, 0, stream>>>(Hbuf, w2b, (void*)Orb,
                                                         slot_score, offsets, counts, 0);
  // shared expert (writes d_out directly)
  dual_glu_gemm<<<dim3(16, 64, 1), 256, 0, stream>>>(xb, sw1b, sw3b, Hs,
                                                     nullptr, nullptr, T_TOK);
  gemm2_kernel<false><<<dim3(8, 64, 1), 256, 0, stream>>>(Hs, sw2b, (void*)d_out,
                                                          nullptr, nullptr, nullptr, T_TOK);
  // combine routed contributions into shared output
  combine_kernel<<<T_TOK, 256, 0, stream>>>(out, Orb, slot2pos);
}